// Round 6
// baseline (247.928 us; speedup 1.0000x reference)
//
#include <hip/hip_runtime.h>
#include <stdint.h>

#define H 1024
#define LSEQ 2048
#define M_TOT 32768          // B*L
#define KDIM 2048            // 2H
#define NKT 64               // K tiles of 32
#define NCT 8                // col tiles of 128
#define NEG_INF_F (-10000000000.0f)

typedef _Float16 f16;
typedef f16 f16x8 __attribute__((ext_vector_type(8)));
typedef float f32x4 __attribute__((ext_vector_type(4)));

// ---------------- ws layout ----------------
// [0, 64K)        sdec f32[16][1024]
// [64K, 64K+1M)   part f32[8][32768]
// [2M, 6M)        weT  tiled fp16 B  [8 ct][64 kt][512 granules x 16B]
// [6M, ...)       encT tiled fp16 A  [rtl][64 kt][1024 granules x 16B] (chunked)
#define WS_SDEC_OFF  0
#define WS_PART_OFF  (64u << 10)
#define WS_WET_OFF   (2u << 20)
#define WS_ENCT_OFF  (6u << 20)

__device__ inline void gload16(const void* g, void* l) {
    __builtin_amdgcn_global_load_lds(
        (const __attribute__((address_space(1))) void*)g,
        (__attribute__((address_space(3))) void*)l, 16, 0, 0);
}

// fast tanh(x)*s with sign fold: sign(x) applied to s
__device__ inline float tanh_mul(float x, float s) {
    float ax = __builtin_fabsf(x);
    float e  = __expf(-2.f * ax);
    float th = (1.f - e) * __builtin_amdgcn_rcpf(1.f + e);
    float sv = __uint_as_float(__float_as_uint(s) ^ (__float_as_uint(x) & 0x80000000u));
    return th * sv;
}

// W_e -> tiled/swizzled fp16. granule g: ct=g>>15, kt=(g>>9)&63, p=g&511,
// row=p>>2, slot=(p&3)^((row>>1)&3). 256 blocks x 256 thr x 4.
__global__ __launch_bounds__(256) void wecvt_tiled(const float* __restrict__ attn_w,
                                                   f16* __restrict__ weT) {
    int g = blockIdx.x * 1024 + threadIdx.x;
    #pragma unroll
    for (int q = 0; q < 4; ++q, g += 256) {
        int ct  = g >> 15;
        int rem = g & 32767;
        int kt  = rem >> 9;
        int p   = rem & 511;
        int row = p >> 2;
        int sl  = (p & 3) ^ ((row >> 1) & 3);
        const float* s = attn_w + (size_t)(ct * 128 + row) * 3072 + 1024 + kt * 32 + sl * 8;
        float4 a = *(const float4*)s;
        float4 b = *(const float4*)(s + 4);
        f16x8 h = { (f16)a.x,(f16)a.y,(f16)a.z,(f16)a.w,(f16)b.x,(f16)b.y,(f16)b.z,(f16)b.w };
        *(f16x8*)(weT + (size_t)g * 8) = h;
    }
}

// encoder_out -> tiled/swizzled fp16 (one row-chunk of rts row-tiles).
__global__ __launch_bounds__(256) void enccvt(const float* __restrict__ enc,
                                              f16* __restrict__ encT, int rt0) {
    int g = blockIdx.x * 2048 + threadIdx.x;
    #pragma unroll
    for (int q = 0; q < 8; ++q, g += 256) {
        int rtl = g >> 16;
        int rem = g & 65535;
        int kt  = rem >> 10;
        int p   = rem & 1023;
        int row = p >> 2;
        int sl  = (p & 3) ^ ((row >> 1) & 3);
        const float* s = enc + (size_t)((rt0 + rtl) * 256 + row) * 2048 + kt * 32 + sl * 8;
        float4 a = *(const float4*)s;
        float4 b = *(const float4*)(s + 4);
        f16x8 h = { (f16)a.x,(f16)a.y,(f16)a.z,(f16)a.w,(f16)b.x,(f16)b.y,(f16)b.z,(f16)b.w };
        *(f16x8*)(encT + (size_t)g * 8) = h;
    }
}

// score_dec[b][h] = attn_b[h] + sum_k v[b][k] * attn_w[h][k]
__global__ void sdec_kernel(const float* __restrict__ v,
                            const float* __restrict__ attn_w,
                            const float* __restrict__ attn_b,
                            float* __restrict__ sdec) {
    int gid  = blockIdx.x * 4 + (threadIdx.x >> 6);
    int lane = threadIdx.x & 63;
    int b = gid >> 10;
    int h = gid & 1023;
    const float* vr = v + b * 1024;
    const float* wr = attn_w + (size_t)h * 3072;
    float s = 0.f;
    #pragma unroll 4
    for (int k = lane; k < 1024; k += 64) s += vr[k] * wr[k];
    #pragma unroll
    for (int m = 1; m < 64; m <<= 1) s += __shfl_xor(s, m);
    if (lane == 0) sdec[b * 1024 + h] = s + attn_b[h];
}

// GEMM: 256x128 tile, 4 waves (each 64 rows x 128 cols, 4x8 frags), BK=32.
// 3-deep LDS pipeline via global_load_lds + counted vmcnt (T4): stage(t+2)
// issued at iter t; barrier waits vmcnt(6) so next tile's loads stay in flight.
__global__ __launch_bounds__(256, 2) void fused_gemm(
        const f16* __restrict__ encT,   // [rtl][64][1024 granules]
        const f16* __restrict__ weT,    // [8][64][512 granules]
        const float* __restrict__ sdec, // [16][1024]
        const float* __restrict__ vw,   // [1024]
        float* __restrict__ part,       // [NCT][32768]
        int rt0, int nblocks)
{
    // chunked XCD remap (nblocks % 8 == 0)
    const int cpx = nblocks >> 3;
    const int logical = (blockIdx.x & 7) * cpx + (blockIdx.x >> 3);
    const int rtl = logical >> 3;
    const int ct  = logical & 7;

    const int tid = threadIdx.x;
    const int l15 = tid & 15;
    const int l4  = (tid >> 4) & 3;
    const int wv  = tid >> 6;        // 0..3, wave owns rows wv*64..+63, all 128 cols

    // 3 buffers x (A 16KB + B 8KB) = 73.7KB
    __shared__ f16 LDSBUF[3 * 12288];
    __shared__ float red[256];
    char* lds0 = (char*)&LDSBUF[0];

    const char* aTile = (const char*)encT + ((size_t)rtl << 20);   // 64 tiles x 16KB
    const char* bTile = (const char*)weT  + ((size_t)ct  << 19);   // 64 tiles x 8KB

    // fragment read offsets (physical slot = l4 ^ ((row>>1)&3); row%16 == l15)
    const int sl   = l4 ^ ((l15 >> 1) & 3);
    const int aoff = (wv * 64 + l15) * 64 + sl * 16;       // + i*1024
    const int boff = 16384 + l15 * 64 + sl * 16;           // + j*1024

    f32x4 acc[4][8] = {};

    auto stage = [&](int buf, int t) {
        const char* a = aTile + ((size_t)t << 14) + tid * 16;
        char* la = lds0 + buf * 24576 + tid * 16;
        gload16(a,         la);
        gload16(a + 4096,  la + 4096);
        gload16(a + 8192,  la + 8192);
        gload16(a + 12288, la + 12288);
        const char* b = bTile + ((size_t)t << 13) + tid * 16;
        char* lb = la + 16384;
        gload16(b,        lb);
        gload16(b + 4096, lb + 4096);
    };
    auto compute = [&](int buf) {
        const char* base = lds0 + buf * 24576;
        f16x8 af[4], bf[8];
        #pragma unroll
        for (int i = 0; i < 4; ++i) af[i] = *(const f16x8*)(base + aoff + i * 1024);
        #pragma unroll
        for (int j = 0; j < 8; ++j) bf[j] = *(const f16x8*)(base + boff + j * 1024);
        __builtin_amdgcn_s_setprio(1);
        #pragma unroll
        for (int i = 0; i < 4; ++i)
            #pragma unroll
            for (int j = 0; j < 8; ++j)
                acc[i][j] = __builtin_amdgcn_mfma_f32_16x16x32_f16(af[i], bf[j], acc[i][j], 0, 0, 0);
        __builtin_amdgcn_s_setprio(0);
    };

    // ---- prologue: tiles 0,1 in flight; wait tile 0 only ----
    stage(0, 0);
    stage(1, 1);
    asm volatile("s_waitcnt vmcnt(6)" ::: "memory");
    __builtin_amdgcn_s_barrier();
    __builtin_amdgcn_sched_barrier(0);

    int cb = 0, nb = 2;
    #pragma unroll 1
    for (int t = 0; t < NKT - 2; ++t) {
        stage(nb, t + 2);                 // issue-early: lands ~2 iters later
        compute(cb);
        asm volatile("s_waitcnt vmcnt(6)" ::: "memory");   // t+1 done, t+2 in flight
        __builtin_amdgcn_s_barrier();
        __builtin_amdgcn_sched_barrier(0);
        cb = (cb == 2) ? 0 : cb + 1;
        nb = (nb == 2) ? 0 : nb + 1;
    }
    // t = NKT-2: nothing new to stage; ensure last tile landed
    compute(cb);
    asm volatile("s_waitcnt vmcnt(0)" ::: "memory");
    __builtin_amdgcn_s_barrier();
    __builtin_amdgcn_sched_barrier(0);
    cb = (cb == 2) ? 0 : cb + 1;
    // t = NKT-1
    compute(cb);

    // ---------------- epilogue ----------------
    // C/D frag: col = l15, row = l4*4 + r; global row = rowbase+wv*64+i*16+l4*4+r
    const int rowbase = (rt0 + rtl) * 256;
    const int colbase = ct * 128;
    const int bidx = (rt0 + rtl) >> 3;

    float sd[8], vs[8];
    #pragma unroll
    for (int j = 0; j < 8; ++j) {
        const int col = colbase + j * 16 + l15;
        sd[j] = sdec[bidx * 1024 + col];
        vs[j] = vw[col];
    }
    float psum[4][4] = {};
    #pragma unroll
    for (int i = 0; i < 4; ++i)
        #pragma unroll
        for (int j = 0; j < 8; ++j)
            #pragma unroll
            for (int r = 0; r < 4; ++r)
                psum[i][r] += tanh_mul(acc[i][j][r] + sd[j], vs[j]);

    #pragma unroll
    for (int i = 0; i < 4; ++i)
        #pragma unroll
        for (int r = 0; r < 4; ++r) {
            float s = psum[i][r];
            s += __shfl_xor(s, 1); s += __shfl_xor(s, 2);
            s += __shfl_xor(s, 4); s += __shfl_xor(s, 8);
            psum[i][r] = s;
        }

    __syncthreads();   // all LDS pipeline traffic done before red reuse
    if (l15 == 0) {
        #pragma unroll
        for (int i = 0; i < 4; ++i)
            #pragma unroll
            for (int r = 0; r < 4; ++r)
                red[wv * 64 + i * 16 + l4 * 4 + r] = psum[i][r];
    }
    __syncthreads();
    part[(size_t)ct * M_TOT + rowbase + tid] = red[tid];
}

// softmax over L per batch; mask==0 -> -1e10; sums the NCT partials.
__global__ __launch_bounds__(512) void softmax_kernel(
        const float* __restrict__ part, const int* __restrict__ mask,
        float* __restrict__ out) {
    int b = blockIdx.x;
    int tid = threadIdx.x;
    int lane = tid & 63, w = tid >> 6;
    __shared__ float sred[8];

    float vals[4];
    #pragma unroll
    for (int p = 0; p < 4; ++p) {
        int row = b * LSEQ + tid + p * 512;
        float val = 0.f;
        #pragma unroll
        for (int q = 0; q < NCT; ++q) val += part[(size_t)q * M_TOT + row];
        vals[p] = (mask[row] == 0) ? NEG_INF_F : val;
    }
    float mx = fmaxf(fmaxf(vals[0], vals[1]), fmaxf(vals[2], vals[3]));
    #pragma unroll
    for (int m = 1; m < 64; m <<= 1) mx = fmaxf(mx, __shfl_xor(mx, m));
    if (lane == 0) sred[w] = mx;
    __syncthreads();
    float gmax = sred[0];
    #pragma unroll
    for (int i = 1; i < 8; ++i) gmax = fmaxf(gmax, sred[i]);

    float es[4]; float ssum = 0.f;
    #pragma unroll
    for (int p = 0; p < 4; ++p) { es[p] = expf(vals[p] - gmax); ssum += es[p]; }
    #pragma unroll
    for (int m = 1; m < 64; m <<= 1) ssum += __shfl_xor(ssum, m);
    __syncthreads();
    if (lane == 0) sred[w] = ssum;
    __syncthreads();
    float gsum = 0.f;
    #pragma unroll
    for (int i = 0; i < 8; ++i) gsum += sred[i];
    float inv = 1.f / gsum;
    #pragma unroll
    for (int p = 0; p < 4; ++p)
        out[b * LSEQ + tid + p * 512] = es[p] * inv;
}

extern "C" void kernel_launch(void* const* d_in, const int* in_sizes, int n_in,
                              void* d_out, int out_size, void* d_ws, size_t ws_size,
                              hipStream_t stream) {
    const float* enc    = (const float*)d_in[0];
    const int*   mask   = (const int*)  d_in[1];
    const float* v      = (const float*)d_in[2];
    const float* attn_w = (const float*)d_in[3];
    const float* attn_b = (const float*)d_in[4];
    const float* v_w    = (const float*)d_in[5];
    float* out = (float*)d_out;

    char* ws = (char*)d_ws;
    float* sdec = (float*)(ws + WS_SDEC_OFF);
    float* part = (float*)(ws + WS_PART_OFF);
    f16*   weT  = (f16*)  (ws + WS_WET_OFF);
    f16*   encT = (f16*)  (ws + WS_ENCT_OFF);

    hipLaunchKernelGGL(wecvt_tiled, dim3(256),  dim3(256), 0, stream, attn_w, weT);
    hipLaunchKernelGGL(sdec_kernel, dim3(4096), dim3(256), 0, stream, v, attn_w, attn_b, sdec);

    // row-chunking: each row-tile (256 rows) needs 1 MB of encT
    size_t cap = (ws_size > WS_ENCT_OFF) ? (ws_size - WS_ENCT_OFF) : 0;
    int crt = (int)(cap >> 20);
    if (crt > 128) crt = 128;
    if (crt < 1)   crt = 1;
    for (int rt0 = 0; rt0 < 128; rt0 += crt) {
        int rts = (128 - rt0 < crt) ? (128 - rt0) : crt;
        hipLaunchKernelGGL(enccvt,     dim3(rts * 32), dim3(256), 0, stream, enc, encT, rt0);
        hipLaunchKernelGGL(fused_gemm, dim3(rts * 8),  dim3(256), 0, stream,
                           encT, weT, sdec, v_w, part, rt0, rts * 8);
    }
    hipLaunchKernelGGL(softmax_kernel, dim3(16), dim3(512), 0, stream, part, mask, out);
}

// Round 7
// 245.684 us; speedup vs baseline: 1.0091x; 1.0091x over previous
//
#include <hip/hip_runtime.h>
#include <stdint.h>

#define LSEQ 2048
#define M_TOT 32768          // B*L
#define KDIM 2048            // 2H
#define NKT 64               // K tiles of 32
#define NCT 4                // col tiles of 256
#define NEG_INF_F (-10000000000.0f)

typedef _Float16 f16;
typedef f16 f16x8 __attribute__((ext_vector_type(8)));
typedef float f32x4 __attribute__((ext_vector_type(4)));

// ---------------- ws layout ----------------
// [0, 64K)        sdec f32[16][1024]
// [64K, 576K)     part f32[4][32768]
// [2M, 6M)        weT  tiled fp16 B  [4 ct][64 kt][256 col][4 slot x 16B]
// [6M, ...)       encT tiled fp16 A  [rtl][64 kt][256 row][4 slot x 16B] (chunked)
#define WS_SDEC_OFF  0
#define WS_PART_OFF  (64u << 10)
#define WS_WET_OFF   (2u << 20)
#define WS_ENCT_OFF  (6u << 20)

__device__ inline void gload16(const void* g, void* l) {
    __builtin_amdgcn_global_load_lds(
        (const __attribute__((address_space(1))) void*)g,
        (__attribute__((address_space(3))) void*)l, 16, 0, 0);
}

// fast tanh(x)*s with sign fold
__device__ inline float tanh_mul(float x, float s) {
    float ax = __builtin_fabsf(x);
    float e  = __expf(-2.f * ax);
    float th = (1.f - e) * __builtin_amdgcn_rcpf(1.f + e);
    float sv = __uint_as_float(__float_as_uint(s) ^ (__float_as_uint(x) & 0x80000000u));
    return th * sv;
}

// W_e -> tiled/swizzled fp16. granule g: ct=g>>16, kt=(g>>10)&63, p=g&1023,
// row=p>>2, slot_log=(p&3)^(row&3). 256 blocks x 256 thr x 4.
__global__ __launch_bounds__(256) void wecvt_tiled(const float* __restrict__ attn_w,
                                                   f16* __restrict__ weT) {
    int g = blockIdx.x * 1024 + threadIdx.x;
    #pragma unroll
    for (int q = 0; q < 4; ++q, g += 256) {
        int ct  = g >> 16;
        int rem = g & 65535;
        int kt  = rem >> 10;
        int p   = rem & 1023;
        int row = p >> 2;
        int sl  = (p & 3) ^ (row & 3);
        const float* s = attn_w + (size_t)(ct * 256 + row) * 3072 + 1024 + kt * 32 + sl * 8;
        float4 a = *(const float4*)s;
        float4 b = *(const float4*)(s + 4);
        f16x8 h = { (f16)a.x,(f16)a.y,(f16)a.z,(f16)a.w,(f16)b.x,(f16)b.y,(f16)b.z,(f16)b.w };
        *(f16x8*)(weT + (size_t)g * 8) = h;
    }
}

// encoder_out -> tiled/swizzled fp16 (one chunk of rts row-tiles).
__global__ __launch_bounds__(256) void enccvt(const float* __restrict__ enc,
                                              f16* __restrict__ encT, int rt0) {
    int g = blockIdx.x * 2048 + threadIdx.x;
    #pragma unroll
    for (int q = 0; q < 8; ++q, g += 256) {
        int rtl = g >> 16;
        int rem = g & 65535;
        int kt  = rem >> 10;
        int p   = rem & 1023;
        int row = p >> 2;
        int sl  = (p & 3) ^ (row & 3);
        const float* s = enc + (size_t)((rt0 + rtl) * 256 + row) * 2048 + kt * 32 + sl * 8;
        float4 a = *(const float4*)s;
        float4 b = *(const float4*)(s + 4);
        f16x8 h = { (f16)a.x,(f16)a.y,(f16)a.z,(f16)a.w,(f16)b.x,(f16)b.y,(f16)b.z,(f16)b.w };
        *(f16x8*)(encT + (size_t)g * 8) = h;
    }
}

// score_dec[b][h] = attn_b[h] + sum_k v[b][k] * attn_w[h][k]
__global__ void sdec_kernel(const float* __restrict__ v,
                            const float* __restrict__ attn_w,
                            const float* __restrict__ attn_b,
                            float* __restrict__ sdec) {
    int gid  = blockIdx.x * 4 + (threadIdx.x >> 6);
    int lane = threadIdx.x & 63;
    int b = gid >> 10;
    int h = gid & 1023;
    const float* vr = v + b * 1024;
    const float* wr = attn_w + (size_t)h * 3072;
    float s = 0.f;
    #pragma unroll 4
    for (int k = lane; k < 1024; k += 64) s += vr[k] * wr[k];
    #pragma unroll
    for (int m = 1; m < 64; m <<= 1) s += __shfl_xor(s, m);
    if (lane == 0) sdec[b * 1024 + h] = s + attn_b[h];
}

// GEMM: 256x256 tile, 8 waves (2M x 4N), BK=32, 1 block/CU.
// 4-buffer LDS ring staged 3 K-tiles ahead via global_load_lds; 2 phases per
// K-tile, each {ds_reads || 2 gloads; barrier; lgkmcnt(0); 16 MFMA; barrier};
// vmcnt(8) once per K-tile (counted, never drained until tail).
__global__ __launch_bounds__(512, 2) void fused_gemm(
        const f16* __restrict__ encT,   // [rtl][64 kt][16KB]
        const f16* __restrict__ weT,    // [4 ct][64 kt][16KB]
        const float* __restrict__ sdec, // [16][1024]
        const float* __restrict__ vw,   // [1024]
        float* __restrict__ part,       // [NCT][32768]
        int rt0, int nblocks)
{
    // chunked XCD remap (nblocks % 8 == 0)
    const int cpx = nblocks >> 3;
    const int logical = ((int)blockIdx.x & 7) * cpx + ((int)blockIdx.x >> 3);
    const int rtl = logical >> 2;
    const int ct  = logical & 3;

    const int tid = threadIdx.x;
    const int l15 = tid & 15;
    const int l4  = (tid >> 4) & 3;
    const int wv  = tid >> 6;        // 0..7
    const int wm  = wv >> 2;         // 0..1  (128 rows each)
    const int wn  = wv & 3;          // 0..3  (64 cols each)

    __shared__ char lds[4 * 32768];  // ring of 4 K-tile bufs: [A 16KB | B 16KB]
    __shared__ float red[4][256];

    const char* aT = (const char*)encT + ((size_t)rtl << 20);
    const char* bT = (const char*)weT  + ((size_t)ct  << 20);

    // fragment offsets: row 64B, phys slot = l4 ^ (row&3), row&3 == l15&3
    const int swz   = (l4 ^ (l15 & 3)) << 4;
    const int aoff0 = (wm * 128 + l15) * 64 + swz;           // + i*1024
    const int boff0 = 16384 + (wn * 64 + l15) * 64 + swz;    // + j*1024

    f32x4 acc[8][4] = {};
    f16x8 afA[4], afB[4], bf[4];

    auto stageA = [&](int t) {
        const char* s = aT + ((size_t)t << 14) + tid * 16;
        char* d = lds + (t & 3) * 32768 + tid * 16;
        gload16(s, d);
        gload16(s + 8192, d + 8192);
    };
    auto stageB = [&](int t) {
        const char* s = bT + ((size_t)t << 14) + tid * 16;
        char* d = lds + (t & 3) * 32768 + 16384 + tid * 16;
        gload16(s, d);
        gload16(s + 8192, d + 8192);
    };

    // ---- prologue: tiles 0,1,2 in flight; ensure tile 0 landed ----
    stageA(0); stageB(0);
    stageA(1); stageB(1);
    stageA(2); stageB(2);
    asm volatile("s_waitcnt vmcnt(8)" ::: "memory");
    __builtin_amdgcn_s_barrier();
    __builtin_amdgcn_sched_barrier(0);

    #pragma unroll 1
    for (int t = 0; t < NKT; ++t) {
        const char* base = lds + (t & 3) * 32768;
        // ---------- phase 0: i=0..3 x j=0..3 ----------
        #pragma unroll
        for (int i = 0; i < 4; ++i) afA[i] = *(const f16x8*)(base + aoff0 + i * 1024);
        #pragma unroll
        for (int j = 0; j < 4; ++j) bf[j]  = *(const f16x8*)(base + boff0 + j * 1024);
        if (t + 3 < NKT) stageA(t + 3);
        __builtin_amdgcn_s_barrier();
        asm volatile("s_waitcnt lgkmcnt(0)" ::: "memory");
        __builtin_amdgcn_sched_barrier(0);
        __builtin_amdgcn_s_setprio(1);
        #pragma unroll
        for (int i = 0; i < 4; ++i)
            #pragma unroll
            for (int j = 0; j < 4; ++j)
                acc[i][j] = __builtin_amdgcn_mfma_f32_16x16x32_f16(afA[i], bf[j], acc[i][j], 0, 0, 0);
        __builtin_amdgcn_s_setprio(0);
        __builtin_amdgcn_s_barrier();
        // ---------- phase 1: i=4..7 x j=0..3 ----------
        #pragma unroll
        for (int i = 0; i < 4; ++i) afB[i] = *(const f16x8*)(base + aoff0 + (4 + i) * 1024);
        if (t + 3 < NKT) stageB(t + 3);
        __builtin_amdgcn_s_barrier();
        asm volatile("s_waitcnt lgkmcnt(0)" ::: "memory");
        __builtin_amdgcn_sched_barrier(0);
        __builtin_amdgcn_s_setprio(1);
        #pragma unroll
        for (int i = 0; i < 4; ++i)
            #pragma unroll
            for (int j = 0; j < 4; ++j)
                acc[4 + i][j] = __builtin_amdgcn_mfma_f32_16x16x32_f16(afB[i], bf[j], acc[4 + i][j], 0, 0, 0);
        __builtin_amdgcn_s_setprio(0);
        // counted vmcnt once per K-tile: guarantee tile t+1 landed, keep t+2,t+3 in flight
        if (t < NKT - 3)       { asm volatile("s_waitcnt vmcnt(8)" ::: "memory"); }
        else if (t == NKT - 3) { asm volatile("s_waitcnt vmcnt(4)" ::: "memory"); }
        else if (t == NKT - 2) { asm volatile("s_waitcnt vmcnt(0)" ::: "memory"); }
        __builtin_amdgcn_s_barrier();
    }

    // ---------------- epilogue ----------------
    // C/D frag: col = l15, row = l4*4 + r; global row = rowbase + wm*128 + i*16 + l4*4 + r
    const int rowbase = (rt0 + rtl) * 256;
    const int colbase = ct * 256;
    const int bidx = (rt0 + rtl) >> 3;

    float sd[4], vs[4];
    #pragma unroll
    for (int j = 0; j < 4; ++j) {
        const int col = colbase + wn * 64 + j * 16 + l15;
        sd[j] = sdec[bidx * 1024 + col];
        vs[j] = vw[col];
    }
    float psum[8][4] = {};
    #pragma unroll
    for (int i = 0; i < 8; ++i)
        #pragma unroll
        for (int j = 0; j < 4; ++j)
            #pragma unroll
            for (int r = 0; r < 4; ++r)
                psum[i][r] += tanh_mul(acc[i][j][r] + sd[j], vs[j]);

    #pragma unroll
    for (int i = 0; i < 8; ++i)
        #pragma unroll
        for (int r = 0; r < 4; ++r) {
            float s = psum[i][r];
            s += __shfl_xor(s, 1); s += __shfl_xor(s, 2);
            s += __shfl_xor(s, 4); s += __shfl_xor(s, 8);
            psum[i][r] = s;
        }

    __syncthreads();
    if (l15 == 0) {
        #pragma unroll
        for (int i = 0; i < 8; ++i)
            #pragma unroll
            for (int r = 0; r < 4; ++r)
                red[wn][wm * 128 + i * 16 + l4 * 4 + r] = psum[i][r];
    }
    __syncthreads();
    if (tid < 256)
        part[(size_t)ct * M_TOT + rowbase + tid] =
            red[0][tid] + red[1][tid] + red[2][tid] + red[3][tid];
}

// softmax over L per batch; mask==0 -> -1e10; sums the NCT partials.
__global__ __launch_bounds__(512) void softmax_kernel(
        const float* __restrict__ part, const int* __restrict__ mask,
        float* __restrict__ out) {
    int b = blockIdx.x;
    int tid = threadIdx.x;
    int lane = tid & 63, w = tid >> 6;
    __shared__ float sred[8];

    float vals[4];
    #pragma unroll
    for (int p = 0; p < 4; ++p) {
        int row = b * LSEQ + tid + p * 512;
        float val = 0.f;
        #pragma unroll
        for (int q = 0; q < NCT; ++q) val += part[(size_t)q * M_TOT + row];
        vals[p] = (mask[row] == 0) ? NEG_INF_F : val;
    }
    float mx = fmaxf(fmaxf(vals[0], vals[1]), fmaxf(vals[2], vals[3]));
    #pragma unroll
    for (int m = 1; m < 64; m <<= 1) mx = fmaxf(mx, __shfl_xor(mx, m));
    if (lane == 0) sred[w] = mx;
    __syncthreads();
    float gmax = sred[0];
    #pragma unroll
    for (int i = 1; i < 8; ++i) gmax = fmaxf(gmax, sred[i]);

    float es[4]; float ssum = 0.f;
    #pragma unroll
    for (int p = 0; p < 4; ++p) { es[p] = expf(vals[p] - gmax); ssum += es[p]; }
    #pragma unroll
    for (int m = 1; m < 64; m <<= 1) ssum += __shfl_xor(ssum, m);
    __syncthreads();
    if (lane == 0) sred[w] = ssum;
    __syncthreads();
    float gsum = 0.f;
    #pragma unroll
    for (int i = 0; i < 8; ++i) gsum += sred[i];
    float inv = 1.f / gsum;
    #pragma unroll
    for (int p = 0; p < 4; ++p)
        out[b * LSEQ + tid + p * 512] = es[p] * inv;
}

extern "C" void kernel_launch(void* const* d_in, const int* in_sizes, int n_in,
                              void* d_out, int out_size, void* d_ws, size_t ws_size,
                              hipStream_t stream) {
    const float* enc    = (const float*)d_in[0];
    const int*   mask   = (const int*)  d_in[1];
    const float* v      = (const float*)d_in[2];
    const float* attn_w = (const float*)d_in[3];
    const float* attn_b = (const float*)d_in[4];
    const float* v_w    = (const float*)d_in[5];
    float* out = (float*)d_out;

    char* ws = (char*)d_ws;
    float* sdec = (float*)(ws + WS_SDEC_OFF);
    float* part = (float*)(ws + WS_PART_OFF);
    f16*   weT  = (f16*)  (ws + WS_WET_OFF);
    f16*   encT = (f16*)  (ws + WS_ENCT_OFF);

    hipLaunchKernelGGL(wecvt_tiled, dim3(256),  dim3(256), 0, stream, attn_w, weT);
    hipLaunchKernelGGL(sdec_kernel, dim3(4096), dim3(256), 0, stream, v, attn_w, attn_b, sdec);

    // row-chunking: each row-tile (256 rows) needs 1 MB of encT; keep rts even
    size_t cap = (ws_size > WS_ENCT_OFF) ? (ws_size - WS_ENCT_OFF) : 0;
    int crt = (int)(cap >> 20);
    if (crt > 128) crt = 128;
    crt &= ~1;
    if (crt < 2) crt = 2;
    for (int rt0 = 0; rt0 < 128; rt0 += crt) {
        int rts = (128 - rt0 < crt) ? (128 - rt0) : crt;
        hipLaunchKernelGGL(enccvt,     dim3(rts * 32), dim3(256), 0, stream, enc, encT, rt0);
        hipLaunchKernelGGL(fused_gemm, dim3(rts * 4),  dim3(512), 0, stream,
                           encT, weT, sdec, v_w, part, rt0, rts * 4);
    }
    hipLaunchKernelGGL(softmax_kernel, dim3(16), dim3(512), 0, stream, part, mask, out);
}